// Round 1
// baseline (11364.967 us; speedup 1.0000x reference)
//
#include <hip/hip_runtime.h>
#include <math.h>

// Problem constants (match reference).
constexpr int B_ = 4, S_ = 4096, D_ = 1024, FF_ = 2048, V_ = 512;
constexpr int L_ = 2, OD_ = 64, GD_ = 8, PD_ = 72;
constexpr float SCALE_ = 0.03125f;   // 1/sqrt(1024)

// ---------------- small helpers ----------------

__device__ __forceinline__ float blockReduceSum(float v, float* sh) {
    #pragma unroll
    for (int off = 32; off > 0; off >>= 1) v += __shfl_down(v, off, 64);
    int t = threadIdx.x;
    if ((t & 63) == 0) sh[t >> 6] = v;
    __syncthreads();
    float r = sh[0] + sh[1] + sh[2] + sh[3];
    __syncthreads();
    return r;
}

__device__ __forceinline__ float blockReduceMax(float v, float* sh) {
    #pragma unroll
    for (int off = 32; off > 0; off >>= 1) v = fmaxf(v, __shfl_down(v, off, 64));
    int t = threadIdx.x;
    if ((t & 63) == 0) sh[t >> 6] = v;
    __syncthreads();
    float r = fmaxf(fmaxf(sh[0], sh[1]), fmaxf(sh[2], sh[3]));
    __syncthreads();
    return r;
}

// ---------------- embedding side ----------------

// One block per batch: projrow[b][:] = concat(occ_emb[occ], gen_emb[gen]) @ proj_W + proj_b
__global__ __launch_bounds__(256) void proj_kernel(
    const int* __restrict__ occ, const int* __restrict__ gen,
    const float* __restrict__ oe, const float* __restrict__ ge,
    const float* __restrict__ W, const float* __restrict__ pb,
    float* __restrict__ out)
{
    __shared__ float agg[PD_];
    int b = blockIdx.x, t = threadIdx.x;
    if (t < OD_)       agg[t] = oe[occ[b] * OD_ + t];
    else if (t < PD_)  agg[t] = ge[gen[b] * GD_ + (t - OD_)];
    __syncthreads();
    float4 acc = reinterpret_cast<const float4*>(pb)[t];
    #pragma unroll 8
    for (int k = 0; k < PD_; ++k) {
        float a = agg[k];
        float4 w = reinterpret_cast<const float4*>(W + k * D_)[t];
        acc.x = fmaf(a, w.x, acc.x); acc.y = fmaf(a, w.y, acc.y);
        acc.z = fmaf(a, w.z, acc.z); acc.w = fmaf(a, w.w, acc.w);
    }
    reinterpret_cast<float4*>(out + b * D_)[t] = acc;
}

// x[row][:] = tok_emb[ids[row]] + pos_emb[s] + projrow[b]
__global__ __launch_bounds__(256) void embed_kernel(
    const int* __restrict__ ids, const float* __restrict__ tok,
    const float* __restrict__ pos, const float* __restrict__ pr,
    float* __restrict__ x)
{
    int row = blockIdx.x, t = threadIdx.x;
    int b = row >> 12;                 // S = 4096
    int s = row & (S_ - 1);
    int tk = ids[row];
    float4 a = reinterpret_cast<const float4*>(tok + (size_t)tk * D_)[t];
    float4 p = reinterpret_cast<const float4*>(pos + (size_t)s * D_)[t];
    float4 q = reinterpret_cast<const float4*>(pr + (size_t)b * D_)[t];
    a.x += p.x + q.x; a.y += p.y + q.y; a.z += p.z + q.z; a.w += p.w + q.w;
    reinterpret_cast<float4*>(x + (size_t)row * D_)[t] = a;
}

// ---------------- layernorm ----------------

__global__ __launch_bounds__(256) void ln_kernel(
    const float* __restrict__ x, float* __restrict__ n,
    const float* __restrict__ w, const float* __restrict__ b)
{
    __shared__ float sh[4];
    int row = blockIdx.x, t = threadIdx.x;
    float4 v = reinterpret_cast<const float4*>(x + (size_t)row * D_)[t];
    float s = v.x + v.y + v.z + v.w;
    float q = v.x * v.x + v.y * v.y + v.z * v.z + v.w * v.w;
    float ssum = blockReduceSum(s, sh);
    float qsum = blockReduceSum(q, sh);
    float mean = ssum * (1.0f / D_);
    float var  = qsum * (1.0f / D_) - mean * mean;
    float rstd = rsqrtf(var + 1e-5f);
    float4 w4 = reinterpret_cast<const float4*>(w)[t];
    float4 b4 = reinterpret_cast<const float4*>(b)[t];
    float4 o;
    o.x = (v.x - mean) * rstd * w4.x + b4.x;
    o.y = (v.y - mean) * rstd * w4.y + b4.y;
    o.z = (v.z - mean) * rstd * w4.z + b4.z;
    o.w = (v.w - mean) * rstd * w4.w + b4.w;
    reinterpret_cast<float4*>(n + (size_t)row * D_)[t] = o;
}

// ---------------- row softmax over S=4096 (scale + additive mask folded in) ----------------

__global__ __launch_bounds__(256) void softmax_kernel(
    float* __restrict__ sc, const float* __restrict__ mask)
{
    __shared__ float sh[4];
    int row = blockIdx.x, t = threadIdx.x;
    float* p = sc + (size_t)row * S_;
    float v[16];
    float mx = -1e30f;
    #pragma unroll
    for (int j = 0; j < 4; ++j) {
        float4 s4 = reinterpret_cast<const float4*>(p)[j * 256 + t];
        float4 m4 = reinterpret_cast<const float4*>(mask)[j * 256 + t];
        int c = j * 4;
        v[c + 0] = s4.x * SCALE_ + (1.0f - m4.x) * (-1e9f);
        v[c + 1] = s4.y * SCALE_ + (1.0f - m4.y) * (-1e9f);
        v[c + 2] = s4.z * SCALE_ + (1.0f - m4.z) * (-1e9f);
        v[c + 3] = s4.w * SCALE_ + (1.0f - m4.w) * (-1e9f);
        mx = fmaxf(mx, fmaxf(fmaxf(v[c], v[c + 1]), fmaxf(v[c + 2], v[c + 3])));
    }
    float gm = blockReduceMax(mx, sh);
    float sum = 0.0f;
    #pragma unroll
    for (int i = 0; i < 16; ++i) { v[i] = __expf(v[i] - gm); sum += v[i]; }
    float gs = blockReduceSum(sum, sh);
    float inv = 1.0f / gs;
    #pragma unroll
    for (int j = 0; j < 4; ++j) {
        int c = j * 4;
        float4 o; o.x = v[c] * inv; o.y = v[c + 1] * inv; o.z = v[c + 2] * inv; o.w = v[c + 3] * inv;
        reinterpret_cast<float4*>(p)[j * 256 + t] = o;
    }
}

// ---------------- fp32 tiled GEMM: C[M][N] = A[M][K] @ Beff[K][N] (+bias, relu, +res) ----------------
// TRANSB=1: Beff[k][n] = Bm[n][k]  (NT: both operands row-major along reduction dim)
// Epilogue order: +bias -> relu -> +res  (only FFN1 uses relu; it has no res)

template<int TRANSB, int HAS_BIAS, int HAS_RES, int RELU>
__global__ __launch_bounds__(256) void gemm_kernel(
    const float* __restrict__ A, const float* __restrict__ Bm,
    float* __restrict__ C, const float* __restrict__ bias,
    const float* __restrict__ res, int M, int N, int K)
{
    __shared__ float As[16][128];   // A-tile transposed: As[kk][m]
    __shared__ float Bs[16][128];   // Beff tile: Bs[kk][n]
    int t = threadIdx.x;
    int n0 = blockIdx.x * 128, m0 = blockIdx.y * 128;
    int tm = t >> 4, tn = t & 15;   // 16x16 thread grid, 8x8 per thread
    float c[8][8];
    #pragma unroll
    for (int i = 0; i < 8; ++i)
        #pragma unroll
        for (int j = 0; j < 8; ++j) c[i][j] = 0.0f;

    for (int k0 = 0; k0 < K; k0 += 16) {
        // stage A (transposed scatter into LDS)
        #pragma unroll
        for (int i = 0; i < 2; ++i) {
            int idx = i * 256 + t;
            int row = idx >> 2;            // 0..127
            int kq  = (idx & 3) * 4;       // 0,4,8,12
            float4 a4 = *reinterpret_cast<const float4*>(A + (size_t)(m0 + row) * K + k0 + kq);
            As[kq + 0][row] = a4.x; As[kq + 1][row] = a4.y;
            As[kq + 2][row] = a4.z; As[kq + 3][row] = a4.w;
        }
        if (TRANSB) {
            #pragma unroll
            for (int i = 0; i < 2; ++i) {
                int idx = i * 256 + t;
                int row = idx >> 2;        // n index
                int kq  = (idx & 3) * 4;
                float4 b4 = *reinterpret_cast<const float4*>(Bm + (size_t)(n0 + row) * K + k0 + kq);
                Bs[kq + 0][row] = b4.x; Bs[kq + 1][row] = b4.y;
                Bs[kq + 2][row] = b4.z; Bs[kq + 3][row] = b4.w;
            }
        } else {
            #pragma unroll
            for (int i = 0; i < 2; ++i) {
                int idx = i * 256 + t;
                int kk = idx >> 5;         // 0..15
                int nq = (idx & 31) * 4;   // 0..124
                *reinterpret_cast<float4*>(&Bs[kk][nq]) =
                    *reinterpret_cast<const float4*>(Bm + (size_t)(k0 + kk) * N + n0 + nq);
            }
        }
        __syncthreads();
        #pragma unroll
        for (int kk = 0; kk < 16; ++kk) {
            float a[8], b[8];
            *reinterpret_cast<float4*>(&a[0]) = *reinterpret_cast<float4*>(&As[kk][tm * 8]);
            *reinterpret_cast<float4*>(&a[4]) = *reinterpret_cast<float4*>(&As[kk][tm * 8 + 4]);
            *reinterpret_cast<float4*>(&b[0]) = *reinterpret_cast<float4*>(&Bs[kk][tn * 8]);
            *reinterpret_cast<float4*>(&b[4]) = *reinterpret_cast<float4*>(&Bs[kk][tn * 8 + 4]);
            #pragma unroll
            for (int i = 0; i < 8; ++i)
                #pragma unroll
                for (int j = 0; j < 8; ++j)
                    c[i][j] = fmaf(a[i], b[j], c[i][j]);
        }
        __syncthreads();
    }

    #pragma unroll
    for (int i = 0; i < 8; ++i) {
        int row = m0 + tm * 8 + i;
        float* cp = C + (size_t)row * N + n0 + tn * 8;
        const float* rp = HAS_RES ? (res + (size_t)row * N + n0 + tn * 8) : nullptr;
        #pragma unroll
        for (int j = 0; j < 8; ++j) {
            float val = c[i][j];
            if (HAS_BIAS) val += bias[n0 + tn * 8 + j];
            if (RELU)     val = fmaxf(val, 0.0f);
            if (HAS_RES)  val += rp[j];
            cp[j] = val;
        }
    }
}

// ---------------- launch ----------------

extern "C" void kernel_launch(void* const* d_in, const int* in_sizes, int n_in,
                              void* d_out, int out_size, void* d_ws, size_t ws_size,
                              hipStream_t stream)
{
    (void)in_sizes; (void)n_in; (void)out_size; (void)ws_size;
    const int*   ids  = (const int*)d_in[0];
    const int*   occ  = (const int*)d_in[1];
    const int*   gen  = (const int*)d_in[2];
    const float* mask = (const float*)d_in[3];
    const float* tok  = (const float*)d_in[4];
    const float* pos  = (const float*)d_in[5];
    const float* oe   = (const float*)d_in[6];
    const float* ge   = (const float*)d_in[7];
    const float* pW   = (const float*)d_in[8];
    const float* pb   = (const float*)d_in[9];
    const float* lnw  = (const float*)d_in[10];
    const float* lnb  = (const float*)d_in[11];
    const float* w1   = (const float*)d_in[12];
    const float* b1   = (const float*)d_in[13];
    const float* w2   = (const float*)d_in[14];
    const float* b2   = (const float*)d_in[15];
    const float* oW   = (const float*)d_in[16];
    const float* ob   = (const float*)d_in[17];
    float* out = (float*)d_out;

    float* ws = (float*)d_ws;
    float* x  = ws;                          // B*S*D
    float* n  = x  + (size_t)B_ * S_ * D_;   // B*S*D
    float* sc = n  + (size_t)B_ * S_ * D_;   // S*S slab, reused as FFN h (S*FF)
    float* pr = sc + (size_t)S_ * S_;        // B*D

    proj_kernel<<<B_, 256, 0, stream>>>(occ, gen, oe, ge, pW, pb, pr);
    embed_kernel<<<B_ * S_, 256, 0, stream>>>(ids, tok, pos, pr, x);

    for (int l = 0; l < L_; ++l) {
        const float* w  = lnw + l * D_;
        const float* bb = lnb + l * D_;
        ln_kernel<<<B_ * S_, 256, 0, stream>>>(x, n, w, bb);
        for (int b = 0; b < B_; ++b) {
            const float* nb = n + (size_t)b * S_ * D_;
            float*       xb = x + (size_t)b * S_ * D_;
            // scores = n_b @ n_b^T   (scale folded into softmax)
            gemm_kernel<1, 0, 0, 0><<<dim3(S_ / 128, S_ / 128), 256, 0, stream>>>(
                nb, nb, sc, nullptr, nullptr, S_, S_, D_);
            softmax_kernel<<<S_, 256, 0, stream>>>(sc, mask + (size_t)b * S_);
            // x_b = probs @ n_b + x_b  (residual in-place)
            gemm_kernel<0, 0, 1, 0><<<dim3(D_ / 128, S_ / 128), 256, 0, stream>>>(
                sc, nb, xb, nullptr, xb, S_, D_, S_);
        }
        ln_kernel<<<B_ * S_, 256, 0, stream>>>(x, n, w, bb);
        for (int b = 0; b < B_; ++b) {
            const float* nb = n + (size_t)b * S_ * D_;
            float*       xb = x + (size_t)b * S_ * D_;
            // h = relu(na @ W1 + b1)
            gemm_kernel<0, 1, 0, 1><<<dim3(FF_ / 128, S_ / 128), 256, 0, stream>>>(
                nb, w1 + (size_t)l * D_ * FF_, sc, b1 + l * FF_, nullptr, S_, FF_, D_);
            // x_b = h @ W2 + b2 + x_b
            gemm_kernel<0, 1, 1, 0><<<dim3(D_ / 128, S_ / 128), 256, 0, stream>>>(
                sc, w2 + (size_t)l * FF_ * D_, xb, b2 + l * D_, xb, S_, D_, FF_);
        }
    }
    // out = x @ out_W + out_b
    gemm_kernel<0, 1, 0, 0><<<dim3(V_ / 128, (B_ * S_) / 128), 256, 0, stream>>>(
        x, oW, out, ob, nullptr, B_ * S_, V_, D_);
}

// Round 2
// 2004.111 us; speedup vs baseline: 5.6708x; 5.6708x over previous
//
#include <hip/hip_runtime.h>
#include <math.h>

// Problem constants (match reference).
constexpr int B_ = 4, S_ = 4096, D_ = 1024, FF_ = 2048, V_ = 512;
constexpr int L_ = 2, OD_ = 64, GD_ = 8, PD_ = 72;
constexpr float SCALE_ = 0.03125f;   // 1/sqrt(1024)

using bf16x8 = __attribute__((ext_vector_type(8))) __bf16;
using bf16x4 = __attribute__((ext_vector_type(4))) __bf16;
using f32x4  = __attribute__((ext_vector_type(4))) float;

// ---------------- helpers ----------------

__device__ __forceinline__ float blockReduceSum(float v, float* sh) {
    #pragma unroll
    for (int off = 32; off > 0; off >>= 1) v += __shfl_down(v, off, 64);
    int t = threadIdx.x;
    if ((t & 63) == 0) sh[t >> 6] = v;
    __syncthreads();
    float r = sh[0] + sh[1] + sh[2] + sh[3];
    __syncthreads();
    return r;
}

__device__ __forceinline__ float blockReduceMax(float v, float* sh) {
    #pragma unroll
    for (int off = 32; off > 0; off >>= 1) v = fmaxf(v, __shfl_down(v, off, 64));
    int t = threadIdx.x;
    if ((t & 63) == 0) sh[t >> 6] = v;
    __syncthreads();
    float r = fmaxf(fmaxf(sh[0], sh[1]), fmaxf(sh[2], sh[3]));
    __syncthreads();
    return r;
}

// async 16B global->LDS (dest must be wave-uniform; HW adds lane*16)
__device__ __forceinline__ void gload_lds16(const void* g, void* lds) {
    __builtin_amdgcn_global_load_lds(
        (const __attribute__((address_space(1))) unsigned int*)g,
        (__attribute__((address_space(3))) unsigned int*)lds,
        16, 0, 0);
}

// ---------------- embedding side ----------------

__global__ __launch_bounds__(256) void proj_kernel(
    const int* __restrict__ occ, const int* __restrict__ gen,
    const float* __restrict__ oe, const float* __restrict__ ge,
    const float* __restrict__ W, const float* __restrict__ pb,
    float* __restrict__ out)
{
    __shared__ float agg[PD_];
    int b = blockIdx.x, t = threadIdx.x;
    if (t < OD_)       agg[t] = oe[occ[b] * OD_ + t];
    else if (t < PD_)  agg[t] = ge[gen[b] * GD_ + (t - OD_)];
    __syncthreads();
    float4 acc = reinterpret_cast<const float4*>(pb)[t];
    #pragma unroll 8
    for (int k = 0; k < PD_; ++k) {
        float a = agg[k];
        float4 w = reinterpret_cast<const float4*>(W + k * D_)[t];
        acc.x = fmaf(a, w.x, acc.x); acc.y = fmaf(a, w.y, acc.y);
        acc.z = fmaf(a, w.z, acc.z); acc.w = fmaf(a, w.w, acc.w);
    }
    reinterpret_cast<float4*>(out + b * D_)[t] = acc;
}

__global__ __launch_bounds__(256) void embed_kernel(
    const int* __restrict__ ids, const float* __restrict__ tok,
    const float* __restrict__ pos, const float* __restrict__ pr,
    float* __restrict__ x)
{
    int row = blockIdx.x, t = threadIdx.x;
    int b = row >> 12;                 // S = 4096
    int s = row & (S_ - 1);
    int tk = ids[row];
    float4 a = reinterpret_cast<const float4*>(tok + (size_t)tk * D_)[t];
    float4 p = reinterpret_cast<const float4*>(pos + (size_t)s * D_)[t];
    float4 q = reinterpret_cast<const float4*>(pr + (size_t)b * D_)[t];
    a.x += p.x + q.x; a.y += p.y + q.y; a.z += p.z + q.z; a.w += p.w + q.w;
    reinterpret_cast<float4*>(x + (size_t)row * D_)[t] = a;
}

// ---------------- layernorm (fp32 in, bf16 out) ----------------

__global__ __launch_bounds__(256) void ln_kernel(
    const float* __restrict__ x, __bf16* __restrict__ nb,
    const float* __restrict__ w, const float* __restrict__ b)
{
    __shared__ float sh[4];
    int row = blockIdx.x, t = threadIdx.x;
    float4 v = reinterpret_cast<const float4*>(x + (size_t)row * D_)[t];
    float s = v.x + v.y + v.z + v.w;
    float q = v.x * v.x + v.y * v.y + v.z * v.z + v.w * v.w;
    float ssum = blockReduceSum(s, sh);
    float qsum = blockReduceSum(q, sh);
    float mean = ssum * (1.0f / D_);
    float var  = qsum * (1.0f / D_) - mean * mean;
    float rstd = rsqrtf(var + 1e-5f);
    float4 w4 = reinterpret_cast<const float4*>(w)[t];
    float4 b4 = reinterpret_cast<const float4*>(b)[t];
    bf16x4 o;
    o[0] = (__bf16)((v.x - mean) * rstd * w4.x + b4.x);
    o[1] = (__bf16)((v.y - mean) * rstd * w4.y + b4.y);
    o[2] = (__bf16)((v.z - mean) * rstd * w4.z + b4.z);
    o[3] = (__bf16)((v.w - mean) * rstd * w4.w + b4.w);
    reinterpret_cast<bf16x4*>(nb + (size_t)row * D_)[t] = o;
}

// ---------------- row softmax: fp32 scores in, bf16 probs out ----------------

__global__ __launch_bounds__(256) void softmax_kernel(
    const float* __restrict__ sc, __bf16* __restrict__ pb,
    const float* __restrict__ mask)
{
    __shared__ float sh[4];
    int row = blockIdx.x, t = threadIdx.x;
    const float* p = sc + (size_t)row * S_;
    float v[16];
    float mx = -1e30f;
    #pragma unroll
    for (int j = 0; j < 4; ++j) {
        float4 s4 = reinterpret_cast<const float4*>(p)[j * 256 + t];
        float4 m4 = reinterpret_cast<const float4*>(mask)[j * 256 + t];
        int c = j * 4;
        v[c + 0] = s4.x * SCALE_ + (1.0f - m4.x) * (-1e9f);
        v[c + 1] = s4.y * SCALE_ + (1.0f - m4.y) * (-1e9f);
        v[c + 2] = s4.z * SCALE_ + (1.0f - m4.z) * (-1e9f);
        v[c + 3] = s4.w * SCALE_ + (1.0f - m4.w) * (-1e9f);
        mx = fmaxf(mx, fmaxf(fmaxf(v[c], v[c + 1]), fmaxf(v[c + 2], v[c + 3])));
    }
    float gm = blockReduceMax(mx, sh);
    float sum = 0.0f;
    #pragma unroll
    for (int i = 0; i < 16; ++i) { v[i] = __expf(v[i] - gm); sum += v[i]; }
    float gs = blockReduceSum(sum, sh);
    float inv = 1.0f / gs;
    __bf16* prow = pb + (size_t)row * S_;
    #pragma unroll
    for (int j = 0; j < 4; ++j) {
        int c = j * 4;
        bf16x4 o;
        o[0] = (__bf16)(v[c + 0] * inv); o[1] = (__bf16)(v[c + 1] * inv);
        o[2] = (__bf16)(v[c + 2] * inv); o[3] = (__bf16)(v[c + 3] * inv);
        reinterpret_cast<bf16x4*>(prow)[j * 256 + t] = o;
    }
}

// ---------------- transpose-cast kernels ----------------

// fp32 [R][C] -> bf16 [C][R] (hi); SPLIT also writes lo = bf16(v - hi)
template<int SPLIT>
__global__ __launch_bounds__(256) void tcast_f32(
    const float* __restrict__ in, __bf16* __restrict__ hi,
    __bf16* __restrict__ lo, int R, int C)
{
    __shared__ float tile[32][33];
    int c0 = blockIdx.x * 32, r0 = blockIdx.y * 32;
    int tx = threadIdx.x & 31, ty = threadIdx.x >> 5;   // ty in 0..7
    #pragma unroll
    for (int i = 0; i < 32; i += 8)
        tile[ty + i][tx] = in[(size_t)(r0 + ty + i) * C + c0 + tx];
    __syncthreads();
    #pragma unroll
    for (int i = 0; i < 32; i += 8) {
        float v = tile[tx][ty + i];
        size_t o = (size_t)(c0 + ty + i) * R + r0 + tx;
        __bf16 h = (__bf16)v;
        hi[o] = h;
        if (SPLIT) lo[o] = (__bf16)(v - (float)h);
    }
}

// bf16 [R][C] -> bf16 [C][R], batched via blockIdx.z
__global__ __launch_bounds__(256) void tcast_b16(
    const __bf16* __restrict__ in, __bf16* __restrict__ out, int R, int C)
{
    __shared__ __bf16 tile[32][33];
    const __bf16* ib = in  + (size_t)blockIdx.z * R * C;
    __bf16*       ob = out + (size_t)blockIdx.z * R * C;
    int c0 = blockIdx.x * 32, r0 = blockIdx.y * 32;
    int tx = threadIdx.x & 31, ty = threadIdx.x >> 5;
    #pragma unroll
    for (int i = 0; i < 32; i += 8)
        tile[ty + i][tx] = ib[(size_t)(r0 + ty + i) * C + c0 + tx];
    __syncthreads();
    #pragma unroll
    for (int i = 0; i < 32; i += 8)
        ob[(size_t)(c0 + ty + i) * R + r0 + tx] = tile[tx][ty + i];
}

// fp32 -> hi/lo bf16 split (elementwise, vectorized)
__global__ __launch_bounds__(256) void splitx_kernel(
    const float* __restrict__ x, __bf16* __restrict__ hi,
    __bf16* __restrict__ lo, long n4)
{
    long i = (long)blockIdx.x * 256 + threadIdx.x;
    if (i >= n4) return;
    float4 v = reinterpret_cast<const float4*>(x)[i];
    bf16x4 h, lw;
    h[0] = (__bf16)v.x; h[1] = (__bf16)v.y; h[2] = (__bf16)v.z; h[3] = (__bf16)v.w;
    lw[0] = (__bf16)(v.x - (float)h[0]); lw[1] = (__bf16)(v.y - (float)h[1]);
    lw[2] = (__bf16)(v.z - (float)h[2]); lw[3] = (__bf16)(v.w - (float)h[3]);
    reinterpret_cast<bf16x4*>(hi)[i] = h;
    reinterpret_cast<bf16x4*>(lo)[i] = lw;
}

// ---------------- MFMA GEMM (NT): C[M][N] = A[M][K] @ BT[N][K]^T ----------------
// 128x128 tile, BK=32, 4 waves (2x2 of 64x64), mfma_f32_16x16x32_bf16.
// A/BT row-major bf16 with leading dims lda/ldb (elements). C fp32 (or bf16).
// Epilogue: +bias -> relu -> +res; ACCUM: C += val.

template<int HAS_BIAS, int HAS_RES, int RELU, int OUT_BF16, int ACCUM>
__global__ __launch_bounds__(256, 2) void mgemm(
    const __bf16* __restrict__ A, const __bf16* __restrict__ Bm,
    void* __restrict__ Cv, const float* __restrict__ bias,
    const float* __restrict__ res, int M, int N, int K, int lda, int ldb)
{
    __shared__ __bf16 As[128 * 32];   // [m][k], 64B rows
    __shared__ __bf16 Bs[128 * 32];   // [n][k]
    const int t = threadIdx.x;
    const int l = t & 63, w = t >> 6;
    const int gm0 = blockIdx.y * 128, gn0 = blockIdx.x * 128;
    const int wm0 = (w >> 1) * 64, wn0 = (w & 1) * 64;
    const int lr = l & 15, lk = l >> 4;   // frag row/col and k-group

    f32x4 acc[4][4] = {};

    for (int k0 = 0; k0 < K; k0 += 32) {
        #pragma unroll
        for (int i = 0; i < 2; ++i) {
            int flat = i * 256 + t;
            int m = flat >> 2, k8 = (flat & 3) * 8;
            gload_lds16(A  + (size_t)(gm0 + m) * lda + k0 + k8,
                        (char*)As + i * 4096 + w * 1024);
            gload_lds16(Bm + (size_t)(gn0 + m) * ldb + k0 + k8,
                        (char*)Bs + i * 4096 + w * 1024);
        }
        __syncthreads();   // drains vmcnt before barrier -> tiles ready
        bf16x8 a[4], b[4];
        #pragma unroll
        for (int f = 0; f < 4; ++f) {
            a[f] = *reinterpret_cast<const bf16x8*>(&As[(wm0 + f * 16 + lr) * 32 + lk * 8]);
            b[f] = *reinterpret_cast<const bf16x8*>(&Bs[(wn0 + f * 16 + lr) * 32 + lk * 8]);
        }
        #pragma unroll
        for (int fi = 0; fi < 4; ++fi)
            #pragma unroll
            for (int fj = 0; fj < 4; ++fj)
                acc[fi][fj] = __builtin_amdgcn_mfma_f32_16x16x32_bf16(
                    a[fi], b[fj], acc[fi][fj], 0, 0, 0);
        __syncthreads();
    }

    float* Cf = (float*)Cv;
    __bf16* Cb = (__bf16*)Cv;
    #pragma unroll
    for (int fi = 0; fi < 4; ++fi) {
        int rbase = gm0 + wm0 + fi * 16 + lk * 4;
        #pragma unroll
        for (int fj = 0; fj < 4; ++fj) {
            int col = gn0 + wn0 + fj * 16 + lr;
            float bv = HAS_BIAS ? bias[col] : 0.0f;
            #pragma unroll
            for (int r = 0; r < 4; ++r) {
                size_t o = (size_t)(rbase + r) * N + col;
                float val = acc[fi][fj][r] + bv;
                if (RELU) val = fmaxf(val, 0.0f);
                if (HAS_RES) val += res[o];
                if (OUT_BF16)    Cb[o] = (__bf16)val;
                else if (ACCUM)  Cf[o] += val;
                else             Cf[o] = val;
            }
        }
    }
}

// ---------------- launch ----------------

extern "C" void kernel_launch(void* const* d_in, const int* in_sizes, int n_in,
                              void* d_out, int out_size, void* d_ws, size_t ws_size,
                              hipStream_t stream)
{
    (void)in_sizes; (void)n_in; (void)out_size; (void)ws_size;
    const int*   ids  = (const int*)d_in[0];
    const int*   occ  = (const int*)d_in[1];
    const int*   gen  = (const int*)d_in[2];
    const float* mask = (const float*)d_in[3];
    const float* tok  = (const float*)d_in[4];
    const float* pos  = (const float*)d_in[5];
    const float* oe   = (const float*)d_in[6];
    const float* ge   = (const float*)d_in[7];
    const float* pW   = (const float*)d_in[8];
    const float* pb   = (const float*)d_in[9];
    const float* lnw  = (const float*)d_in[10];
    const float* lnb  = (const float*)d_in[11];
    const float* w1   = (const float*)d_in[12];
    const float* b1   = (const float*)d_in[13];
    const float* w2   = (const float*)d_in[14];
    const float* b2   = (const float*)d_in[15];
    const float* oW   = (const float*)d_in[16];
    const float* ob   = (const float*)d_in[17];
    float* out = (float*)d_out;

    const size_t SD = (size_t)S_ * D_;
    char* wp = (char*)d_ws;
    float* x    = (float*)wp;  wp += (size_t)B_ * SD * 4;       // fp32 residual stream
    float* sc   = (float*)wp;  wp += (size_t)S_ * S_ * 4;       // fp32 scores slab
    float* pr   = (float*)wp;  wp += (size_t)B_ * D_ * 4;       // proj rows
    __bf16* n_bf  = (__bf16*)wp; wp += (size_t)B_ * SD * 2;     // LN output [B*S][D]
    __bf16* n_bfT = (__bf16*)wp; wp += (size_t)B_ * SD * 2;     // [B][D][S]
    __bf16* slab  = (__bf16*)wp; wp += (size_t)S_ * S_ * 2;     // probs / h
    __bf16* w1t   = (__bf16*)wp; wp += (size_t)L_ * FF_ * D_ * 2;
    __bf16* w2t   = (__bf16*)wp; wp += (size_t)L_ * D_ * FF_ * 2;
    __bf16* owh   = (__bf16*)wp; wp += (size_t)V_ * D_ * 2;
    __bf16* owl   = (__bf16*)wp; wp += (size_t)V_ * D_ * 2;
    __bf16* x_hi  = n_bf;    // aliased: free after final FFN1
    __bf16* x_lo  = n_bfT;   // aliased: free after final PV

    proj_kernel<<<B_, 256, 0, stream>>>(occ, gen, oe, ge, pW, pb, pr);
    embed_kernel<<<B_ * S_, 256, 0, stream>>>(ids, tok, pos, pr, x);

    // weight casts (per launch; deterministic)
    for (int l = 0; l < L_; ++l) {
        tcast_f32<0><<<dim3(FF_ / 32, D_ / 32), 256, 0, stream>>>(
            w1 + (size_t)l * D_ * FF_, w1t + (size_t)l * FF_ * D_, nullptr, D_, FF_);
        tcast_f32<0><<<dim3(D_ / 32, FF_ / 32), 256, 0, stream>>>(
            w2 + (size_t)l * FF_ * D_, w2t + (size_t)l * D_ * FF_, nullptr, FF_, D_);
    }
    tcast_f32<1><<<dim3(V_ / 32, D_ / 32), 256, 0, stream>>>(oW, owh, owl, D_, V_);

    for (int l = 0; l < L_; ++l) {
        const float* w  = lnw + l * D_;
        const float* bb = lnb + l * D_;
        ln_kernel<<<B_ * S_, 256, 0, stream>>>(x, n_bf, w, bb);
        tcast_b16<<<dim3(D_ / 32, S_ / 32, B_), 256, 0, stream>>>(n_bf, n_bfT, S_, D_);
        for (int b = 0; b < B_; ++b) {
            const __bf16* nb  = n_bf  + b * SD;
            const __bf16* nbt = n_bfT + b * SD;
            float*        xb  = x     + b * SD;
            // scores = n @ n^T  (fp32 out; scale folded into softmax)
            mgemm<0, 0, 0, 0, 0><<<dim3(S_ / 128, S_ / 128), 256, 0, stream>>>(
                nb, nb, sc, nullptr, nullptr, S_, S_, D_, D_, D_);
            softmax_kernel<<<S_, 256, 0, stream>>>(sc, slab, mask + (size_t)b * S_);
            // x += probs @ n
            mgemm<0, 1, 0, 0, 0><<<dim3(D_ / 128, S_ / 128), 256, 0, stream>>>(
                slab, nbt, xb, nullptr, xb, S_, D_, S_, S_, S_);
        }
        ln_kernel<<<B_ * S_, 256, 0, stream>>>(x, n_bf, w, bb);
        for (int b = 0; b < B_; ++b) {
            const __bf16* nb = n_bf + b * SD;
            float*        xb = x    + b * SD;
            // h = relu(na @ W1 + b1)   (bf16 out)
            mgemm<1, 0, 1, 1, 0><<<dim3(FF_ / 128, S_ / 128), 256, 0, stream>>>(
                nb, w1t + (size_t)l * FF_ * D_, slab, b1 + l * FF_, nullptr,
                S_, FF_, D_, D_, D_);
            // x += h @ W2 + b2
            mgemm<1, 1, 0, 0, 0><<<dim3(D_ / 128, S_ / 128), 256, 0, stream>>>(
                slab, w2t + (size_t)l * D_ * FF_, xb, b2 + l * D_, xb,
                S_, D_, FF_, FF_, FF_);
        }
    }

    // out = x @ out_W + out_b, split-bf16 (hi*hi + hi*lo + lo*hi)
    splitx_kernel<<<(B_ * SD / 4 + 255) / 256, 256, 0, stream>>>(
        x, x_hi, x_lo, (long)(B_ * SD / 4));
    mgemm<1, 0, 0, 0, 0><<<dim3(V_ / 128, B_ * S_ / 128), 256, 0, stream>>>(
        x_hi, owh, out, ob, nullptr, B_ * S_, V_, D_, D_, D_);
    mgemm<0, 0, 0, 0, 1><<<dim3(V_ / 128, B_ * S_ / 128), 256, 0, stream>>>(
        x_hi, owl, out, nullptr, nullptr, B_ * S_, V_, D_, D_, D_);
    mgemm<0, 0, 0, 0, 1><<<dim3(V_ / 128, B_ * S_ / 128), 256, 0, stream>>>(
        x_lo, owh, out, nullptr, nullptr, B_ * S_, V_, D_, D_, D_);
}

// Round 4
// 1580.946 us; speedup vs baseline: 7.1887x; 1.2677x over previous
//
#include <hip/hip_runtime.h>
#include <math.h>

// Problem constants (match reference).
constexpr int B_ = 4, S_ = 4096, D_ = 1024, FF_ = 2048, V_ = 512;
constexpr int L_ = 2, OD_ = 64, GD_ = 8, PD_ = 72;
constexpr float SCALE_ = 0.03125f;   // 1/sqrt(1024)

using bf16x8 = __attribute__((ext_vector_type(8))) __bf16;
using bf16x4 = __attribute__((ext_vector_type(4))) __bf16;
using f32x4  = __attribute__((ext_vector_type(4))) float;

// ---------------- helpers ----------------

__device__ __forceinline__ float blockReduceSum(float v, float* sh) {
    #pragma unroll
    for (int off = 32; off > 0; off >>= 1) v += __shfl_down(v, off, 64);
    int t = threadIdx.x;
    if ((t & 63) == 0) sh[t >> 6] = v;
    __syncthreads();
    float r = sh[0] + sh[1] + sh[2] + sh[3];
    __syncthreads();
    return r;
}

__device__ __forceinline__ float blockReduceMax(float v, float* sh) {
    #pragma unroll
    for (int off = 32; off > 0; off >>= 1) v = fmaxf(v, __shfl_down(v, off, 64));
    int t = threadIdx.x;
    if ((t & 63) == 0) sh[t >> 6] = v;
    __syncthreads();
    float r = fmaxf(fmaxf(sh[0], sh[1]), fmaxf(sh[2], sh[3]));
    __syncthreads();
    return r;
}

// async 16B global->LDS (dest must be wave-uniform; HW adds lane*16)
__device__ __forceinline__ void gload_lds16(const void* g, void* lds) {
    __builtin_amdgcn_global_load_lds(
        (const __attribute__((address_space(1))) unsigned int*)g,
        (__attribute__((address_space(3))) unsigned int*)lds,
        16, 0, 0);
}

// ---------------- embedding side ----------------

__global__ __launch_bounds__(256) void proj_kernel(
    const int* __restrict__ occ, const int* __restrict__ gen,
    const float* __restrict__ oe, const float* __restrict__ ge,
    const float* __restrict__ W, const float* __restrict__ pb,
    float* __restrict__ out)
{
    __shared__ float agg[PD_];
    int b = blockIdx.x, t = threadIdx.x;
    if (t < OD_)       agg[t] = oe[occ[b] * OD_ + t];
    else if (t < PD_)  agg[t] = ge[gen[b] * GD_ + (t - OD_)];
    __syncthreads();
    float4 acc = reinterpret_cast<const float4*>(pb)[t];
    #pragma unroll 8
    for (int k = 0; k < PD_; ++k) {
        float a = agg[k];
        float4 w = reinterpret_cast<const float4*>(W + k * D_)[t];
        acc.x = fmaf(a, w.x, acc.x); acc.y = fmaf(a, w.y, acc.y);
        acc.z = fmaf(a, w.z, acc.z); acc.w = fmaf(a, w.w, acc.w);
    }
    reinterpret_cast<float4*>(out + b * D_)[t] = acc;
}

__global__ __launch_bounds__(256) void embed_kernel(
    const int* __restrict__ ids, const float* __restrict__ tok,
    const float* __restrict__ pos, const float* __restrict__ pr,
    float* __restrict__ x)
{
    int row = blockIdx.x, t = threadIdx.x;
    int b = row >> 12;                 // S = 4096
    int s = row & (S_ - 1);
    int tk = ids[row];
    float4 a = reinterpret_cast<const float4*>(tok + (size_t)tk * D_)[t];
    float4 p = reinterpret_cast<const float4*>(pos + (size_t)s * D_)[t];
    float4 q = reinterpret_cast<const float4*>(pr + (size_t)b * D_)[t];
    a.x += p.x + q.x; a.y += p.y + q.y; a.z += p.z + q.z; a.w += p.w + q.w;
    reinterpret_cast<float4*>(x + (size_t)row * D_)[t] = a;
}

// ---------------- layernorm (fp32 in, bf16 out) ----------------

__global__ __launch_bounds__(256) void ln_kernel(
    const float* __restrict__ x, __bf16* __restrict__ nb,
    const float* __restrict__ w, const float* __restrict__ b)
{
    __shared__ float sh[4];
    int row = blockIdx.x, t = threadIdx.x;
    float4 v = reinterpret_cast<const float4*>(x + (size_t)row * D_)[t];
    float s = v.x + v.y + v.z + v.w;
    float q = v.x * v.x + v.y * v.y + v.z * v.z + v.w * v.w;
    float ssum = blockReduceSum(s, sh);
    float qsum = blockReduceSum(q, sh);
    float mean = ssum * (1.0f / D_);
    float var  = qsum * (1.0f / D_) - mean * mean;
    float rstd = rsqrtf(var + 1e-5f);
    float4 w4 = reinterpret_cast<const float4*>(w)[t];
    float4 b4 = reinterpret_cast<const float4*>(b)[t];
    bf16x4 o;
    o[0] = (__bf16)((v.x - mean) * rstd * w4.x + b4.x);
    o[1] = (__bf16)((v.y - mean) * rstd * w4.y + b4.y);
    o[2] = (__bf16)((v.z - mean) * rstd * w4.z + b4.z);
    o[3] = (__bf16)((v.w - mean) * rstd * w4.w + b4.w);
    reinterpret_cast<bf16x4*>(nb + (size_t)row * D_)[t] = o;
}

// ---------------- in-place row softmax on bf16 scores (scale+mask folded) ------
// Block = one row; all 16 values loaded to registers before any write -> safe.

__global__ __launch_bounds__(256) void softmax_b16(
    __bf16* __restrict__ sc, const float* __restrict__ mask)
{
    __shared__ float sh[4];
    int row = blockIdx.x, t = threadIdx.x;
    __bf16* p = sc + (size_t)row * S_;
    float v[16];
    float mx = -1e30f;
    #pragma unroll
    for (int j = 0; j < 2; ++j) {
        bf16x8 s8 = reinterpret_cast<const bf16x8*>(p)[j * 256 + t];
        int e2 = (j * 256 + t) * 2;
        float4 ma = reinterpret_cast<const float4*>(mask)[e2];
        float4 mb = reinterpret_cast<const float4*>(mask)[e2 + 1];
        float mf[8] = {ma.x, ma.y, ma.z, ma.w, mb.x, mb.y, mb.z, mb.w};
        #pragma unroll
        for (int i = 0; i < 8; ++i) {
            float s = (float)s8[i] * SCALE_ + (1.0f - mf[i]) * (-1e9f);
            v[j * 8 + i] = s;
            mx = fmaxf(mx, s);
        }
    }
    float gm = blockReduceMax(mx, sh);
    float sum = 0.0f;
    #pragma unroll
    for (int i = 0; i < 16; ++i) { v[i] = __expf(v[i] - gm); sum += v[i]; }
    float gs = blockReduceSum(sum, sh);
    float inv = 1.0f / gs;
    #pragma unroll
    for (int j = 0; j < 2; ++j) {
        bf16x8 o;
        #pragma unroll
        for (int i = 0; i < 8; ++i) o[i] = (__bf16)(v[j * 8 + i] * inv);
        reinterpret_cast<bf16x8*>(p)[j * 256 + t] = o;
    }
}

// ---------------- transpose-cast kernels ----------------

template<int SPLIT>
__global__ __launch_bounds__(256) void tcast_f32(
    const float* __restrict__ in, __bf16* __restrict__ hi,
    __bf16* __restrict__ lo, int R, int C)
{
    __shared__ float tile[32][33];
    int c0 = blockIdx.x * 32, r0 = blockIdx.y * 32;
    int tx = threadIdx.x & 31, ty = threadIdx.x >> 5;
    #pragma unroll
    for (int i = 0; i < 32; i += 8)
        tile[ty + i][tx] = in[(size_t)(r0 + ty + i) * C + c0 + tx];
    __syncthreads();
    #pragma unroll
    for (int i = 0; i < 32; i += 8) {
        float v = tile[tx][ty + i];
        size_t o = (size_t)(c0 + ty + i) * R + r0 + tx;
        __bf16 h = (__bf16)v;
        hi[o] = h;
        if (SPLIT) lo[o] = (__bf16)(v - (float)h);
    }
}

__global__ __launch_bounds__(256) void tcast_b16(
    const __bf16* __restrict__ in, __bf16* __restrict__ out, int R, int C)
{
    __shared__ __bf16 tile[32][33];
    const __bf16* ib = in  + (size_t)blockIdx.z * R * C;
    __bf16*       ob = out + (size_t)blockIdx.z * R * C;
    int c0 = blockIdx.x * 32, r0 = blockIdx.y * 32;
    int tx = threadIdx.x & 31, ty = threadIdx.x >> 5;
    #pragma unroll
    for (int i = 0; i < 32; i += 8)
        tile[ty + i][tx] = ib[(size_t)(r0 + ty + i) * C + c0 + tx];
    __syncthreads();
    #pragma unroll
    for (int i = 0; i < 32; i += 8)
        ob[(size_t)(c0 + ty + i) * R + r0 + tx] = tile[tx][ty + i];
}

__global__ __launch_bounds__(256) void splitx_kernel(
    const float* __restrict__ x, __bf16* __restrict__ hi,
    __bf16* __restrict__ lo, long n4)
{
    long i = (long)blockIdx.x * 256 + threadIdx.x;
    if (i >= n4) return;
    float4 v = reinterpret_cast<const float4*>(x)[i];
    bf16x4 h, lw;
    h[0] = (__bf16)v.x; h[1] = (__bf16)v.y; h[2] = (__bf16)v.z; h[3] = (__bf16)v.w;
    lw[0] = (__bf16)(v.x - (float)h[0]); lw[1] = (__bf16)(v.y - (float)h[1]);
    lw[2] = (__bf16)(v.z - (float)h[2]); lw[3] = (__bf16)(v.w - (float)h[3]);
    reinterpret_cast<bf16x4*>(hi)[i] = h;
    reinterpret_cast<bf16x4*>(lo)[i] = lw;
}

// ---------------- 2-phase MFMA GEMM (NT): C[M][N] = A[M][K] @ BT[N][K]^T --------
// 128x128 tile, BK=64, double-buffered LDS (64KB -> 2 blocks/CU), 4 waves.
// Prefetch tile kt+1 issued BEFORE computing tile kt; single vmcnt(0)+barrier
// per K-tile (the __syncthreads at loop end) so load latency hides under MFMA.
// z-batched via blockIdx.z with element strides sA/sB/sC (C and res share sC).

template<int HAS_BIAS, int HAS_RES, int RELU, int OUT_BF16, int ACCUM>
__global__ __launch_bounds__(256, 2) void mgemm2(
    const __bf16* __restrict__ A, const __bf16* __restrict__ Bm,
    void* __restrict__ Cv, const float* __restrict__ bias,
    const float* __restrict__ res,
    int M, int N, int K, int lda, int ldb,
    size_t sA, size_t sB, size_t sC)
{
    __shared__ __bf16 As[2][128 * 64];
    __shared__ __bf16 Bs[2][128 * 64];
    const int t = threadIdx.x;
    const int w = t >> 6, l = t & 63;
    const int lr = l & 15, lk = l >> 4;
    const int gm0 = blockIdx.y * 128, gn0 = blockIdx.x * 128;
    const int wm0 = (w >> 1) * 64, wn0 = (w & 1) * 64;
    const int z = blockIdx.z;
    A  += (size_t)z * sA;
    Bm += (size_t)z * sB;

    const int srow = t >> 3;        // 0..31 (row within 32-row stage chunk)
    const int sk   = (t & 7) * 8;   // k-offset of this lane's 16B chunk

    auto stage = [&](int buf, int k0) {
        #pragma unroll
        for (int i = 0; i < 4; ++i) {
            gload_lds16(A  + (size_t)(gm0 + i * 32 + srow) * lda + k0 + sk,
                        (char*)(&As[buf][0]) + i * 4096 + w * 1024);
            gload_lds16(Bm + (size_t)(gn0 + i * 32 + srow) * ldb + k0 + sk,
                        (char*)(&Bs[buf][0]) + i * 4096 + w * 1024);
        }
    };

    f32x4 acc[4][4] = {};
    stage(0, 0);
    __syncthreads();                 // vmcnt(0) drain + barrier: buf0 ready
    const int nkt = K >> 6;
    int buf = 0;
    for (int kt = 0; kt < nkt; ++kt) {
        if (kt + 1 < nkt) stage(buf ^ 1, (kt + 1) << 6);   // prefetch next tile
        #pragma unroll
        for (int ks = 0; ks < 2; ++ks) {
            bf16x8 a[4], b[4];
            #pragma unroll
            for (int f = 0; f < 4; ++f) {
                a[f] = *reinterpret_cast<const bf16x8*>(
                    &As[buf][(wm0 + f * 16 + lr) * 64 + ks * 32 + lk * 8]);
                b[f] = *reinterpret_cast<const bf16x8*>(
                    &Bs[buf][(wn0 + f * 16 + lr) * 64 + ks * 32 + lk * 8]);
            }
            #pragma unroll
            for (int fi = 0; fi < 4; ++fi)
                #pragma unroll
                for (int fj = 0; fj < 4; ++fj)
                    acc[fi][fj] = __builtin_amdgcn_mfma_f32_16x16x32_bf16(
                        a[fi], b[fj], acc[fi][fj], 0, 0, 0);
        }
        __syncthreads();   // drains prefetch (vmcnt) + reads (lgkm), then barrier
        buf ^= 1;
    }

    float*  Cf = (float*)Cv  + (size_t)z * sC;
    __bf16* Cb = (__bf16*)Cv + (size_t)z * sC;
    const float* rp = HAS_RES ? (res + (size_t)z * sC) : nullptr;
    #pragma unroll
    for (int fi = 0; fi < 4; ++fi) {
        int rbase = gm0 + wm0 + fi * 16 + lk * 4;
        #pragma unroll
        for (int fj = 0; fj < 4; ++fj) {
            int col = gn0 + wn0 + fj * 16 + lr;
            float bv = HAS_BIAS ? bias[col] : 0.0f;
            #pragma unroll
            for (int r = 0; r < 4; ++r) {
                size_t o = (size_t)(rbase + r) * N + col;
                float val = acc[fi][fj][r] + bv;
                if (RELU) val = fmaxf(val, 0.0f);
                if (HAS_RES) val += rp[o];
                if (OUT_BF16)    Cb[o] = (__bf16)val;
                else if (ACCUM)  Cf[o] += val;
                else             Cf[o] = val;
            }
        }
    }
}

// ---------------- launch ----------------

extern "C" void kernel_launch(void* const* d_in, const int* in_sizes, int n_in,
                              void* d_out, int out_size, void* d_ws, size_t ws_size,
                              hipStream_t stream)
{
    (void)in_sizes; (void)n_in; (void)out_size; (void)ws_size;
    const int*   ids  = (const int*)d_in[0];
    const int*   occ  = (const int*)d_in[1];
    const int*   gen  = (const int*)d_in[2];
    const float* mask = (const float*)d_in[3];
    const float* tok  = (const float*)d_in[4];
    const float* pos  = (const float*)d_in[5];
    const float* oe   = (const float*)d_in[6];
    const float* ge   = (const float*)d_in[7];
    const float* pW   = (const float*)d_in[8];
    const float* pb   = (const float*)d_in[9];
    const float* lnw  = (const float*)d_in[10];
    const float* lnb  = (const float*)d_in[11];
    const float* w1   = (const float*)d_in[12];
    const float* b1   = (const float*)d_in[13];
    const float* w2   = (const float*)d_in[14];
    const float* b2   = (const float*)d_in[15];
    const float* oW   = (const float*)d_in[16];
    const float* ob   = (const float*)d_in[17];
    float* out = (float*)d_out;

    const size_t SD = (size_t)S_ * D_;
    const size_t SS = (size_t)S_ * S_;
    // Workspace total ~210 MB (R2's proven layout was 242 MB; R3's 274 MB crashed).
    char* wp = (char*)d_ws;
    float* x    = (float*)wp;  wp += (size_t)B_ * SD * 4;      // fp32 residual (64MB)
    float* pr   = (float*)wp;  wp += (size_t)B_ * D_ * 4;      // proj rows
    __bf16* n_bf  = (__bf16*)wp; wp += (size_t)B_ * SD * 2;    // LN out [B*S][D] (32MB)
    __bf16* n_bfT = (__bf16*)wp; wp += (size_t)B_ * SD * 2;    // [B][D][S] (32MB)
    __bf16* big   = (__bf16*)wp; wp += 2 * SS * 2;             // scores/probs pair | FFN h (64MB)
    __bf16* w1t   = (__bf16*)wp; wp += (size_t)L_ * FF_ * D_ * 2;  // 8MB
    __bf16* w2t   = (__bf16*)wp; wp += (size_t)L_ * D_ * FF_ * 2;  // 8MB
    __bf16* owh   = (__bf16*)wp; wp += (size_t)V_ * D_ * 2;        // 1MB
    __bf16* owl   = (__bf16*)wp; wp += (size_t)V_ * D_ * 2;        // 1MB
    __bf16* x_hi  = n_bf;    // aliased: n_bf dead after final FFN1
    __bf16* x_lo  = n_bfT;   // aliased: n_bfT dead after final PV

    proj_kernel<<<B_, 256, 0, stream>>>(occ, gen, oe, ge, pW, pb, pr);
    embed_kernel<<<B_ * S_, 256, 0, stream>>>(ids, tok, pos, pr, x);

    for (int l = 0; l < L_; ++l) {
        tcast_f32<0><<<dim3(FF_ / 32, D_ / 32), 256, 0, stream>>>(
            w1 + (size_t)l * D_ * FF_, w1t + (size_t)l * FF_ * D_, nullptr, D_, FF_);
        tcast_f32<0><<<dim3(D_ / 32, FF_ / 32), 256, 0, stream>>>(
            w2 + (size_t)l * FF_ * D_, w2t + (size_t)l * D_ * FF_, nullptr, FF_, D_);
    }
    tcast_f32<1><<<dim3(V_ / 32, D_ / 32), 256, 0, stream>>>(oW, owh, owl, D_, V_);

    for (int l = 0; l < L_; ++l) {
        const float* w  = lnw + l * D_;
        const float* bb = lnb + l * D_;
        ln_kernel<<<B_ * S_, 256, 0, stream>>>(x, n_bf, w, bb);
        tcast_b16<<<dim3(D_ / 32, S_ / 32, B_), 256, 0, stream>>>(n_bf, n_bfT, S_, D_);
        for (int p = 0; p < 2; ++p) {            // batch pairs
            for (int q = 0; q < 2; ++q) {
                int b = 2 * p + q;
                // scores (bf16) = n_b @ n_b^T  (scale folded into softmax)
                mgemm2<0, 0, 0, 1, 0><<<dim3(S_ / 128, S_ / 128, 1), 256, 0, stream>>>(
                    n_bf + b * SD, n_bf + b * SD, big + q * SS, nullptr, nullptr,
                    S_, S_, D_, D_, D_, 0, 0, 0);
                // in-place softmax: bf16 scores -> bf16 probs
                softmax_b16<<<S_, 256, 0, stream>>>(big + q * SS, mask + (size_t)b * S_);
            }
            // x += probs @ n  for both batches of the pair (z = 2)
            mgemm2<0, 1, 0, 0, 0><<<dim3(D_ / 128, S_ / 128, 2), 256, 0, stream>>>(
                big, n_bfT + (size_t)(2 * p) * SD, x + (size_t)(2 * p) * SD,
                nullptr, x + (size_t)(2 * p) * SD,
                S_, D_, S_, S_, S_, SS, SD, SD);
        }
        ln_kernel<<<B_ * S_, 256, 0, stream>>>(x, n_bf, w, bb);
        // h = relu(na @ W1 + b1), all batches, bf16 out into big
        mgemm2<1, 0, 1, 1, 0><<<dim3(FF_ / 128, (B_ * S_) / 128, 1), 256, 0, stream>>>(
            n_bf, w1t + (size_t)l * FF_ * D_, big, b1 + l * FF_, nullptr,
            B_ * S_, FF_, D_, D_, D_, 0, 0, 0);
        // x += h @ W2 + b2
        mgemm2<1, 1, 0, 0, 0><<<dim3(D_ / 128, (B_ * S_) / 128, 1), 256, 0, stream>>>(
            big, w2t + (size_t)l * D_ * FF_, x, b2 + l * D_, x,
            B_ * S_, D_, FF_, FF_, FF_, 0, 0, 0);
    }

    // out = x @ out_W + out_b, split-bf16 (hi*hi + hi*lo + lo*hi)
    splitx_kernel<<<(int)((B_ * SD / 4 + 255) / 256), 256, 0, stream>>>(
        x, x_hi, x_lo, (long)(B_ * SD / 4));
    mgemm2<1, 0, 0, 0, 0><<<dim3(V_ / 128, (B_ * S_) / 128, 1), 256, 0, stream>>>(
        x_hi, owh, out, ob, nullptr, B_ * S_, V_, D_, D_, D_, 0, 0, 0);
    mgemm2<0, 0, 0, 0, 1><<<dim3(V_ / 128, (B_ * S_) / 128, 1), 256, 0, stream>>>(
        x_hi, owl, out, nullptr, nullptr, B_ * S_, V_, D_, D_, D_, 0, 0, 0);
    mgemm2<0, 0, 0, 0, 1><<<dim3(V_ / 128, (B_ * S_) / 128, 1), 256, 0, stream>>>(
        x_lo, owh, out, nullptr, nullptr, B_ * S_, V_, D_, D_, D_, 0, 0, 0);
}